// Round 2
// baseline (8024.504 us; speedup 1.0000x reference)
//
#include <hip/hip_runtime.h>

#define NB 32
#define NA 3
#define NT 30
#define NCLS 80
#define NSB (3 * NB)          // 96 (scale, b) pairs
#define NPT (NSB * NT)        // 2880 record slots

struct __align__(16) Rec {
    float tx, ty, tw, th;              // 16 B
    unsigned long long lo, hi;         // 16 B  class-union bits
    int key, scale, valid, pad;        // 16 B
};

struct Accum {
    double sq[3];
    double bce[3];
    int    cnt[3];
    int    pad;
};

__device__ inline void atomicAddD(double* addr, double val) {
    unsigned long long* a = (unsigned long long*)addr;
    unsigned long long old = *a, assumed;
    do {
        assumed = old;
        double nv = __longlong_as_double(assumed) + val;
        old = atomicCAS(a, assumed, __double_as_longlong(nv));
    } while (old != assumed);
}

// ---- Kernel A: one block per (scale, b). Keys, last-wins dedup, records. ----
__global__ __launch_bounds__(64) void yolo_prep(
    const float* __restrict__ a0, const float* __restrict__ a1, const float* __restrict__ a2,
    const float* __restrict__ tg, Accum* acc, Rec* __restrict__ recs)
{
    const int sb = blockIdx.x;
    const int s = sb / NB, b = sb % NB;
    const int tid = threadIdx.x;

    __shared__ float st[NT * 5];
    __shared__ float anc[NA * 2];
    __shared__ int   skey[NT];

    if (sb == 0 && tid < 3) {            // zero accumulators (A completes before B starts)
        acc->sq[tid] = 0.0; acc->bce[tid] = 0.0; acc->cnt[tid] = 0;
    }
    for (int i = tid; i < NT * 5; i += 64) st[i] = tg[b * NT * 5 + i];
    if (tid < NA * 2) {
        const float* ap = (s == 0) ? a0 : (s == 1) ? a1 : a2;
        anc[tid] = ap[tid];
    }
    __syncthreads();

    int   best = 0;
    float gx = 0.f, gy = 0.f, gw = 0.f, gh = 0.f;
    const int g = 13 << s;
    const float gf = (float)g;

    if (tid < NT) {
        const float* tp = &st[tid * 5];
        gx = tp[0] * gf;
        gy = tp[1] * gf;
        gw = fabsf(tp[2] - tp[0]) * (416.0f * gf);
        gh = fabsf(tp[3] - tp[1]) * (416.0f * gf);
        float bestiou = -1.0f;
        for (int a = 0; a < NA; ++a) {
            float aw = anc[a * 2], ah = anc[a * 2 + 1];
            float inter = fminf(aw, gw) * fminf(ah, gh);
            float uni = 1e-8f + aw * ah + gw * gh - inter;
            float iou = inter / uni;
            if (iou > bestiou) { bestiou = iou; best = a; }   // first-max wins (argmax)
        }
        int gi = (int)gx, gj = (int)gy;
        skey[tid] = ((b * NA + best) * g + gi) * g + gj;
    }
    __syncthreads();

    if (tid < NT) {
        const int key = skey[tid];
        unsigned long long lo = 0ull, hi = 0ull;
        bool win = true;
        for (int t2 = 0; t2 < NT; ++t2) {
            if (skey[t2] == key) {
                if (t2 > tid) { win = false; break; }   // later target overwrites
                int c = (int)st[t2 * 5 + 4];
                if (c < 64) lo |= 1ull << c; else hi |= 1ull << (c - 64);
            }
        }
        Rec r;
        r.valid = win ? 1 : 0;
        r.key = key; r.scale = s; r.pad = 0;
        r.lo = lo; r.hi = hi;
        r.tx = gx - floorf(gx);
        r.ty = gy - floorf(gy);
        r.tw = win ? logf(gw / anc[best * 2])     : 0.f;
        r.th = win ? logf(gh / anc[best * 2 + 1]) : 0.f;
        recs[sb * NT + tid] = r;
    }
}

// ---- Kernel B: one wave per record slot; lanes cover the 85 cell elements. ----
__global__ __launch_bounds__(256) void yolo_accum(
    const float* __restrict__ o0, const float* __restrict__ o1, const float* __restrict__ o2,
    Accum* acc, const Rec* __restrict__ recs)
{
    const int slot = blockIdx.x * 4 + (threadIdx.x >> 6);
    const int lane = threadIdx.x & 63;
    if (slot >= NPT) return;
    const Rec r = recs[slot];
    if (!r.valid) return;

    const float* op = (r.scale == 0) ? o0 : (r.scale == 1) ? o1 : o2;
    const float* cell = op + (size_t)r.key * (5 + NCLS);

    double vsq = 0.0, vbce = 0.0;
    {
        float x = cell[lane];                       // elements 0..63
        if (lane < 4) {
            float t = (lane == 0) ? r.tx : (lane == 1) ? r.ty : (lane == 2) ? r.tw : r.th;
            float d = x - t;
            vsq = (double)d * d;
        } else if (lane >= 5) {
            int c = lane - 5;                       // classes 0..58
            bool one = (r.lo >> c) & 1ull;
            float p = fminf(fmaxf(x, 1e-7f), 1.0f - 1e-7f);
            vbce = (double)(one ? -logf(p) : -logf(1.0f - p));
        }
    }
    if (lane < 21) {
        float x = cell[64 + lane];                  // elements 64..84, classes 59..79
        int c = 59 + lane;
        bool one = (c < 64) ? ((r.lo >> c) & 1ull) : ((r.hi >> (c - 64)) & 1ull);
        float p = fminf(fmaxf(x, 1e-7f), 1.0f - 1e-7f);
        vbce += (double)(one ? -logf(p) : -logf(1.0f - p));
    }

    for (int off = 32; off > 0; off >>= 1) {
        vsq  += __shfl_down(vsq, off);
        vbce += __shfl_down(vbce, off);
    }
    if (lane == 0) {
        atomicAddD(&acc->sq[r.scale], vsq);
        atomicAddD(&acc->bce[r.scale], vbce);
        atomicAdd(&acc->cnt[r.scale], 1);
    }
}

// ---- Kernel C: combine. ----
__global__ void yolo_final(const Accum* __restrict__ acc, float* __restrict__ dout) {
    double loss = 0.0;
    for (int s = 0; s < 3; ++s) {
        double c = (acc->cnt[s] > 0) ? (double)acc->cnt[s] : 1.0;
        loss += acc->sq[s] / c + acc->bce[s] / (c * (double)NCLS);
    }
    dout[0] = (float)loss;
}

extern "C" void kernel_launch(void* const* d_in, const int* in_sizes, int n_in,
                              void* d_out, int out_size, void* d_ws, size_t ws_size,
                              hipStream_t stream) {
    const float* o0 = (const float*)d_in[0];
    const float* o1 = (const float*)d_in[1];
    const float* o2 = (const float*)d_in[2];
    const float* a0 = (const float*)d_in[3];
    const float* a1 = (const float*)d_in[4];
    const float* a2 = (const float*)d_in[5];
    const float* tg = (const float*)d_in[6];
    float* out = (float*)d_out;

    Accum* acc = (Accum*)d_ws;
    Rec*   recs = (Rec*)((char*)d_ws + 64);

    hipLaunchKernelGGL(yolo_prep,  dim3(NSB),      dim3(64),  0, stream, a0, a1, a2, tg, acc, recs);
    hipLaunchKernelGGL(yolo_accum, dim3(NPT / 4),  dim3(256), 0, stream, o0, o1, o2, acc, recs);
    hipLaunchKernelGGL(yolo_final, dim3(1),        dim3(1),   0, stream, acc, out);
}

// Round 3
// 22.833 us; speedup vs baseline: 351.4491x; 351.4491x over previous
//
#include <hip/hip_runtime.h>

#define NB 32
#define NA 3
#define NT 30
#define NCLS 80
#define NSB (3 * NB)          // 96 (scale, b) pairs
#define NPT (NSB * NT)        // 2880 record slots

struct __align__(16) Rec {
    float tx, ty, tw, th;              // 16 B
    unsigned long long lo, hi;         // 16 B  class-union bits
    int key, scale, valid, pad;        // 16 B
};

// ---- Kernel A: one block per (scale, b). Keys, last-wins dedup, records. ----
__global__ __launch_bounds__(64) void yolo_prep(
    const float* __restrict__ a0, const float* __restrict__ a1, const float* __restrict__ a2,
    const float* __restrict__ tg, Rec* __restrict__ recs)
{
    const int sb = blockIdx.x;
    const int s = sb / NB, b = sb % NB;
    const int tid = threadIdx.x;

    __shared__ float st[NT * 5];
    __shared__ float anc[NA * 2];
    __shared__ int   skey[NT];

    for (int i = tid; i < NT * 5; i += 64) st[i] = tg[b * NT * 5 + i];
    if (tid < NA * 2) {
        const float* ap = (s == 0) ? a0 : (s == 1) ? a1 : a2;
        anc[tid] = ap[tid];
    }
    __syncthreads();

    int   best = 0;
    float gx = 0.f, gy = 0.f, gw = 0.f, gh = 0.f;
    const int g = 13 << s;
    const float gf = (float)g;

    if (tid < NT) {
        const float* tp = &st[tid * 5];
        gx = tp[0] * gf;
        gy = tp[1] * gf;
        gw = fabsf(tp[2] - tp[0]) * (416.0f * gf);
        gh = fabsf(tp[3] - tp[1]) * (416.0f * gf);
        float bestiou = -1.0f;
        for (int a = 0; a < NA; ++a) {
            float aw = anc[a * 2], ah = anc[a * 2 + 1];
            float inter = fminf(aw, gw) * fminf(ah, gh);
            float uni = 1e-8f + aw * ah + gw * gh - inter;
            float iou = inter / uni;
            if (iou > bestiou) { bestiou = iou; best = a; }   // first-max wins (argmax)
        }
        int gi = (int)gx, gj = (int)gy;
        skey[tid] = ((b * NA + best) * g + gi) * g + gj;
    }
    __syncthreads();

    if (tid < NT) {
        const int key = skey[tid];
        unsigned long long lo = 0ull, hi = 0ull;
        bool win = true;
        for (int t2 = 0; t2 < NT; ++t2) {
            if (skey[t2] == key) {
                if (t2 > tid) { win = false; break; }   // later target overwrites
                int c = (int)st[t2 * 5 + 4];
                if (c < 64) lo |= 1ull << c; else hi |= 1ull << (c - 64);
            }
        }
        Rec r;
        r.valid = win ? 1 : 0;
        r.key = key; r.scale = s; r.pad = 0;
        r.lo = lo; r.hi = hi;
        r.tx = gx - floorf(gx);
        r.ty = gy - floorf(gy);
        r.tw = win ? logf(gw / anc[best * 2])     : 0.f;
        r.th = win ? logf(gh / anc[best * 2 + 1]) : 0.f;
        recs[sb * NT + tid] = r;
    }
}

// ---- Kernel B: one wave per slot; lanes cover the 85 cell elements.
//      NO atomics: each wave writes its {sq, bce} partial to parts[slot]. ----
__global__ __launch_bounds__(256) void yolo_accum(
    const float* __restrict__ o0, const float* __restrict__ o1, const float* __restrict__ o2,
    const Rec* __restrict__ recs, double2* __restrict__ parts)
{
    const int slot = blockIdx.x * 4 + (threadIdx.x >> 6);
    const int lane = threadIdx.x & 63;
    if (slot >= NPT) return;
    const Rec r = recs[slot];
    if (!r.valid) {
        if (lane == 0) parts[slot] = make_double2(0.0, 0.0);   // must overwrite poison
        return;
    }

    const float* op = (r.scale == 0) ? o0 : (r.scale == 1) ? o1 : o2;
    const float* cell = op + (size_t)r.key * (5 + NCLS);

    double vsq = 0.0, vbce = 0.0;
    {
        float x = cell[lane];                       // elements 0..63
        if (lane < 4) {
            float t = (lane == 0) ? r.tx : (lane == 1) ? r.ty : (lane == 2) ? r.tw : r.th;
            float d = x - t;
            vsq = (double)d * d;
        } else if (lane >= 5) {
            int c = lane - 5;                       // classes 0..58
            bool one = (r.lo >> c) & 1ull;
            float p = fminf(fmaxf(x, 1e-7f), 1.0f - 1e-7f);
            vbce = (double)(one ? -logf(p) : -logf(1.0f - p));
        }
    }
    if (lane < 21) {
        float x = cell[64 + lane];                  // elements 64..84, classes 59..79
        int c = 59 + lane;
        bool one = (c < 64) ? ((r.lo >> c) & 1ull) : ((r.hi >> (c - 64)) & 1ull);
        float p = fminf(fmaxf(x, 1e-7f), 1.0f - 1e-7f);
        vbce += (double)(one ? -logf(p) : -logf(1.0f - p));
    }

    for (int off = 32; off > 0; off >>= 1) {
        vsq  += __shfl_down(vsq, off);
        vbce += __shfl_down(vbce, off);
    }
    if (lane == 0) parts[slot] = make_double2(vsq, vbce);
}

// ---- Kernel C: single-block deterministic reduction of 2880 partials. ----
__global__ __launch_bounds__(1024) void yolo_final(
    const Rec* __restrict__ recs, const double2* __restrict__ parts,
    float* __restrict__ dout)
{
    const int tid = threadIdx.x;
    const int wid = tid >> 6, lane = tid & 63;

    double l_sq[3] = {0, 0, 0}, l_bce[3] = {0, 0, 0};
    int    l_cnt[3] = {0, 0, 0};

    for (int slot = tid; slot < NPT; slot += 1024) {
        double2 p = parts[slot];
        int s = slot / (NB * NT);
        l_sq[s]  += p.x;
        l_bce[s] += p.y;
        l_cnt[s] += recs[slot].valid;
    }

    __shared__ double s_sq[16][3], s_bce[16][3];
    __shared__ int    s_cnt[16][3];

    for (int s = 0; s < 3; ++s) {
        double vsq = l_sq[s], vbce = l_bce[s];
        int vc = l_cnt[s];
        for (int off = 32; off > 0; off >>= 1) {
            vsq  += __shfl_down(vsq, off);
            vbce += __shfl_down(vbce, off);
            vc   += __shfl_down(vc, off);
        }
        if (lane == 0) { s_sq[wid][s] = vsq; s_bce[wid][s] = vbce; s_cnt[wid][s] = vc; }
    }
    __syncthreads();

    if (tid == 0) {
        double loss = 0.0;
        for (int s = 0; s < 3; ++s) {
            double sq = 0.0, bce = 0.0; int cnt = 0;
            for (int w = 0; w < 16; ++w) { sq += s_sq[w][s]; bce += s_bce[w][s]; cnt += s_cnt[w][s]; }
            double c = (cnt > 0) ? (double)cnt : 1.0;
            loss += sq / c + bce / (c * (double)NCLS);
        }
        dout[0] = (float)loss;
    }
}

extern "C" void kernel_launch(void* const* d_in, const int* in_sizes, int n_in,
                              void* d_out, int out_size, void* d_ws, size_t ws_size,
                              hipStream_t stream) {
    const float* o0 = (const float*)d_in[0];
    const float* o1 = (const float*)d_in[1];
    const float* o2 = (const float*)d_in[2];
    const float* a0 = (const float*)d_in[3];
    const float* a1 = (const float*)d_in[4];
    const float* a2 = (const float*)d_in[5];
    const float* tg = (const float*)d_in[6];
    float* out = (float*)d_out;

    Rec*     recs  = (Rec*)d_ws;                                  // 138,240 B
    double2* parts = (double2*)((char*)d_ws + NPT * sizeof(Rec)); //  46,080 B

    hipLaunchKernelGGL(yolo_prep,  dim3(NSB),     dim3(64),   0, stream, a0, a1, a2, tg, recs);
    hipLaunchKernelGGL(yolo_accum, dim3(NPT / 4), dim3(256),  0, stream, o0, o1, o2, recs, parts);
    hipLaunchKernelGGL(yolo_final, dim3(1),       dim3(1024), 0, stream, recs, parts, out);
}